// Round 9
// baseline (330720.239 us; speedup 1.0000x reference)
//
#include <hip/hip_runtime.h>
#include <math.h>

#define TENC 400
#define TMEL 800
#define NMEL 80
#define ENCD 768
#define PRE  256
#define ARNN 1024
#define DRNN 1024
#define ATTD 128
#define NBLK 256u

__device__ __forceinline__ float4 ld4(const float* p){ return *(const float4*)p; }
__device__ __forceinline__ float dot4(float4 a, float4 b){
  return a.x*b.x + a.y*b.y + a.z*b.z + a.w*b.w;
}
__device__ __forceinline__ float sigmf(float x){ return 1.f/(1.f + __expf(-x)); }

// =================== software grid barrier (device-scope) ===================
// Monotonic arrival counter + release flag. cnt/rel zeroed before each launch.
__device__ __forceinline__ void gbar(unsigned* cnt, unsigned* rel, unsigned phase)
{
  __syncthreads();
  if (threadIdx.x == 0) {
    __threadfence();                                   // release prior writes
    unsigned my = atomicAdd(cnt, 1u) + 1u;             // device-scope
    if (my == phase * NBLK) {
      __hip_atomic_store(rel, phase, __ATOMIC_RELEASE, __HIP_MEMORY_SCOPE_AGENT);
    } else {
      while (__hip_atomic_load(rel, __ATOMIC_ACQUIRE, __HIP_MEMORY_SCOPE_AGENT) < phase)
        __builtin_amdgcn_s_sleep(1);
    }
    __threadfence();                                   // acquire
  }
  __syncthreads();
}

// =================== prenet: xsT[t][k=256][b=32] ===================
__global__ __launch_bounds__(256) void prenet_kernel(
    const float* __restrict__ din, const float* __restrict__ w1,
    const float* __restrict__ w2, float* __restrict__ xsT)
{
  int t = blockIdx.x;
  __shared__ float f_s[32*80];
  __shared__ float p_s[32*257];
  for (int id = threadIdx.x; id < 32*80; id += 256) {
    int b = id / 80, m = id - b*80;
    f_s[id] = (t == 0) ? 0.f : din[b*(NMEL*TMEL) + m*TMEL + (t-1)];
  }
  __syncthreads();
  for (int b = 0; b < 32; ++b) {
    int k = threadIdx.x;
    float acc = 0.f;
    #pragma unroll 4
    for (int m = 0; m < 80; ++m) acc += f_s[b*80+m] * w1[k*80+m];
    p_s[b*257+k] = fmaxf(acc, 0.f);
  }
  __syncthreads();
  int b = threadIdx.x & 31, jslot = threadIdx.x >> 5;
  for (int jj = 0; jj < 32; ++jj) {
    int j = jslot*32 + jj;
    const float* w2r = w2 + j*256;
    float acc = 0.f;
    #pragma unroll 4
    for (int kk = 0; kk < 256; ++kk) acc += p_s[b*257+kk] * w2r[kk];
    xsT[(size_t)t*8192 + j*32 + b] = fmaxf(acc, 0.f);
  }
}

// =================== pmem[b][t][128] ===================
__global__ __launch_bounds__(256) void pmem_kernel(
  const float* __restrict__ mem, const float* __restrict__ mw, float* __restrict__ pmem)
{
  int b = blockIdx.y, tc = blockIdx.x;
  int a = threadIdx.x & 127, th = threadIdx.x >> 7;
  for (int i = 0; i < 8; ++i) {
    int tt = tc*16 + th + 2*i;
    const float* mrow = mem + (size_t)b*(TENC*ENCD) + (size_t)tt*ENCD;
    const float* wrow = mw + a*ENCD;
    float acc = 0.f;
    #pragma unroll 4
    for (int e4 = 0; e4 < ENCD; e4 += 4) acc += dot4(ld4(mrow+e4), ld4(wrow+e4));
    pmem[b*(TENC*ATTD) + tt*ATTD + a] = acc;
  }
}

// =================== q_wT[k=1024][a=128] ===================
__global__ __launch_bounds__(256) void qwt_kernel(
  const float* __restrict__ qw, float* __restrict__ qwT)
{
  int a = blockIdx.x;
  for (int i = 0; i < 4; ++i) {
    int k = threadIdx.x + i*256;
    qwT[k*128 + a] = qw[a*1024 + k];
  }
}

// =================== args struct for persistent kernel ===================
struct DecArgs {
  const float *xsT, *pmem, *qwT;
  const float *awih, *awhh, *abih, *abhh;
  const float *dwih, *dwhh, *dbih, *dbhh;
  const float *cw, *ldw, *vw;
  const int*  mlen;
  const float *pw, *pb, *gw, *gb;
  float *ahT, *acT, *dhT, *dh, *dcT;
  float *ctxT, *ctx2, *aw, *awcb, *e;
  const float *memory;
  float *out_mel, *out_gate, *out_align;
  unsigned *bar_cnt, *bar_rel;
};

// =================== fused GEMM+cell (validated gemm16 body, permuted rows) ===================
__device__ __forceinline__ void gemm_cell(int u0,
  const float* __restrict__ xtA, int cA, const float* __restrict__ xtB, int cB,
  const float* __restrict__ xtC, int cC,
  const float* __restrict__ wih, int kih, const float* __restrict__ whh,
  const float* __restrict__ bih, const float* __restrict__ bhh,
  float* __restrict__ cT, float* __restrict__ hT_out, float* __restrict__ h_row,
  float* smem)
{
  float4* Xs = (float4*)smem;          // 2048 float4
  float*  Ws = smem + 8192;            // 16*264
  float*  G  = smem + 12416;           // 16*32
  const int tid = threadIdx.x;
  const int wave = tid >> 6, lane = tid & 63;
  const int klane = lane & 31, half = lane >> 5;
  const int tile = wave*2 + half;
  const int bg = tile & 3, rg = tile >> 2;
  const int b0 = bg*8, r0 = rg*8;
  float acc[8][8];
  #pragma unroll
  for (int i = 0; i < 8; ++i)
    #pragma unroll
    for (int j = 0; j < 8; ++j) acc[i][j] = 0.f;

  const int scol = tid & 7, skr = tid >> 3;
  const int swr = tid >> 4, skk = (tid & 15)*16;
  const int jrow = ((swr >> 2)*1024) + u0 + (swr & 3);   // permuted gate row
  const int nC = cA + cB + cC;

  for (int c = 0; c < nC; ++c) {
    const float* xsrc; int ck;
    if (c < cA)            { xsrc = xtA; ck = c; }
    else if (c < cA + cB)  { xsrc = xtB; ck = c - cA; }
    else                   { xsrc = xtC; ck = c - cA - cB; }
    #pragma unroll
    for (int i = 0; i < 8; ++i) {
      int k = skr + 32*i;
      float4 v = *(const float4*)(xsrc + (size_t)(ck*256 + k)*32 + scol*4);
      Xs[k*8 + (scol ^ (k & 7))] = v;
    }
    {
      int kglob = c*256 + skk;
      const float* wr = (kglob < kih) ? (wih + (size_t)jrow*kih + kglob)
                                      : (whh + (size_t)jrow*1024 + (kglob - kih));
      float* wd = Ws + swr*264 + skk;
      #pragma unroll
      for (int q = 0; q < 4; ++q) *(float4*)(wd + q*4) = ld4(wr + q*4);
    }
    __syncthreads();
    #pragma unroll
    for (int kk = 0; kk < 8; ++kk) {
      int k = klane + 32*kk;
      float4 x0 = Xs[k*8 + ((bg*2)     ^ (klane & 7))];
      float4 x1 = Xs[k*8 + ((bg*2 + 1) ^ (klane & 7))];
      float w[8];
      #pragma unroll
      for (int r = 0; r < 8; ++r) w[r] = Ws[(r0 + r)*264 + k];
      float xb[8] = {x0.x, x0.y, x0.z, x0.w, x1.x, x1.y, x1.z, x1.w};
      #pragma unroll
      for (int r = 0; r < 8; ++r)
        #pragma unroll
        for (int bb = 0; bb < 8; ++bb)
          acc[bb][r] += xb[bb] * w[r];
    }
    __syncthreads();
  }
  #pragma unroll
  for (int m = 16; m >= 1; m >>= 1)
    #pragma unroll
    for (int bb = 0; bb < 8; ++bb)
      #pragma unroll
      for (int r = 0; r < 8; ++r)
        acc[bb][r] += __shfl_xor(acc[bb][r], m);
  if (klane == 0) {
    #pragma unroll
    for (int r = 0; r < 8; ++r) {
      float4 lo = make_float4(acc[0][r], acc[1][r], acc[2][r], acc[3][r]);
      float4 hi = make_float4(acc[4][r], acc[5][r], acc[6][r], acc[7][r]);
      *(float4*)(G + (r0 + r)*32 + b0)     = lo;
      *(float4*)(G + (r0 + r)*32 + b0 + 4) = hi;
    }
  }
  __syncthreads();
  if (tid < 128) {
    int du = tid >> 5, b = tid & 31;
    int u = u0 + du;
    float gi = G[(0*4+du)*32 + b] + bih[u]        + bhh[u];
    float gf = G[(1*4+du)*32 + b] + bih[1024+u]   + bhh[1024+u];
    float gg = G[(2*4+du)*32 + b] + bih[2048+u]   + bhh[2048+u];
    float go = G[(3*4+du)*32 + b] + bih[3072+u]   + bhh[3072+u];
    float c  = cT[u*32 + b];
    float cn = sigmf(gf)*c + sigmf(gi)*tanhf(gg);
    float h  = sigmf(go)*tanhf(cn);
    cT[u*32 + b]     = cn;
    hT_out[u*32 + b] = h;
    if (h_row) h_row[b*1024 + u] = h;
  }
  __syncthreads();
}

// =================== projection helper ===================
__device__ __forceinline__ void proj_task(int d, const float* dh, const float* ctx,
    const float* proj_w, const float* proj_b, const float* gate_w, const float* gate_b,
    float* out_mel, float* out_gate, int t)
{
  if (d >= 32*81) return;
  int b = d / 81, r = d - b*81;
  const float* w   = (r < 80) ? (proj_w + r*1792) : gate_w;
  const float* dhr = dh + b*DRNN;
  const float* cxr = ctx + b*ENCD;
  float acc = 0.f;
  #pragma unroll 4
  for (int k = 0; k < 1024; k += 4) acc += dot4(ld4(dhr+k), ld4(w+k));
  #pragma unroll 4
  for (int k = 0; k < 768;  k += 4) acc += dot4(ld4(cxr+k), ld4(w+1024+k));
  if (r < 80) out_mel[(b*80 + r)*TMEL + t] = acc + proj_b[r];
  else        out_gate[b*TMEL + t]         = acc + gate_b[0];
}

// =================== energies phase ===================
__device__ __forceinline__ void energies_phase(int bk, const DecArgs& p,
  const float* ahT_cur, const float* awc_old, float* smem)
{
  int b = bk >> 3, c8 = bk & 7;
  int t0 = c8 * 50;
  float* pq_s  = smem;          // 128
  float* part  = smem + 128;    // 256
  float* aw_s  = smem + 384;    // 80
  float* awc_s = smem + 464;    // 80
  float* loc_s = smem + 544;    // 50*33
  float* epart = smem + 2194;   // 50*4
  int tid = threadIdx.x;
  {
    int a = tid & 127, kh = tid >> 7;
    float acc = 0.f;
    for (int u = kh*512; u < kh*512 + 512; ++u)
      acc += ahT_cur[u*32 + b] * p.qwT[u*128 + a];
    part[tid] = acc;
  }
  if (tid >= 96) {              // halo: 160 threads -> i in [0,160)
    int i = tid - 96;
    int h = (i < 80) ? i : i - 80;
    bool isC = i >= 80;
    int g = t0 - 15 + h;
    float v = (g >= 0 && g < TENC) ? (isC ? awc_old[b*TENC+g] : p.aw[b*TENC+g]) : 0.f;
    if (isC) awc_s[h] = v; else aw_s[h] = v;
  }
  __syncthreads();
  if (tid < 128) pq_s[tid] = part[tid] + part[tid + 128];
  for (int id = tid; id < 50*32; id += 256) {
    int tl = id >> 5, f = id & 31;
    const float* w0 = p.cw + f*62;
    float acc = 0.f;
    #pragma unroll
    for (int k = 0; k < 31; ++k)
      acc += aw_s[tl+k]*w0[k] + awc_s[tl+k]*w0[31+k];
    loc_s[tl*33 + f] = acc;
  }
  __syncthreads();
  if (tid < 200) {
    int tl = tid >> 2, qa = tid & 3;
    int tt = t0 + tl;
    const float* pm = p.pmem + b*(TENC*ATTD) + tt*ATTD;
    float s = 0.f;
    for (int a = qa*32; a < qa*32 + 32; ++a) {
      const float* lw = p.ldw + a*32;
      float pl = 0.f;
      #pragma unroll 8
      for (int f = 0; f < 32; ++f) pl += loc_s[tl*33 + f] * lw[f];
      s += p.vw[a] * tanhf(pq_s[a] + pm[a] + pl);
    }
    epart[tl*4 + qa] = s;
  }
  __syncthreads();
  if (tid < 50) {
    int tt = t0 + tid;
    float v = epart[tid*4] + epart[tid*4+1] + epart[tid*4+2] + epart[tid*4+3];
    if (tt >= p.mlen[b]) v = -1000000000.0f;
    p.e[b*TENC + tt] = v;
  }
  __syncthreads();
}

// =================== softmax + ctx phase ===================
__device__ __forceinline__ void softmax_ctx_phase(int bk, int t, const DecArgs& p,
  const float* awc_old, float* awc_new, float* ctx_cur, float* smem)
{
  int b = bk / 6, ch = bk % 6;
  int tid = threadIdx.x;
  float* red  = smem;          // 256
  float* aw_s = smem + 256;    // 400
  float v0 = p.e[b*TENC + tid];
  float v1 = (tid + 256 < TENC) ? p.e[b*TENC + tid + 256] : -3.0e38f;
  red[tid] = fmaxf(v0, v1); __syncthreads();
  for (int s = 128; s > 0; s >>= 1) {
    if (tid < s) red[tid] = fmaxf(red[tid], red[tid+s]);
    __syncthreads();
  }
  float mx = red[0]; __syncthreads();
  float p0 = __expf(v0 - mx);
  float p1 = (tid + 256 < TENC) ? __expf(v1 - mx) : 0.f;
  red[tid] = p0 + p1; __syncthreads();
  for (int s = 128; s > 0; s >>= 1) {
    if (tid < s) red[tid] += red[tid+s];
    __syncthreads();
  }
  float inv = 1.f / red[0];
  aw_s[tid] = p0 * inv;
  if (tid + 256 < TENC) aw_s[tid + 256] = p1 * inv;
  __syncthreads();
  int j = ch*128 + (tid & 127), h = tid >> 7;
  float acc = 0.f;
  const float* mrow = p.memory + (size_t)b*(TENC*ENCD) + j;
  #pragma unroll 4
  for (int tt = h*200; tt < h*200 + 200; ++tt)
    acc += aw_s[tt] * mrow[(size_t)tt*ENCD];
  red[tid] = acc; __syncthreads();
  if (h == 0) {
    float tot = red[tid] + red[tid + 128];
    p.ctxT[j*32 + b]   = tot;
    ctx_cur[b*ENCD + j] = tot;
  }
  if (ch == 0) {
    for (int i = tid; i < TENC; i += 256) {
      float a = aw_s[i];
      p.aw[b*TENC + i] = a;
      awc_new[b*TENC + i] = awc_old[b*TENC + i] + a;
      p.out_align[((size_t)b*TMEL + t)*TENC + i] = a;
    }
  }
  __syncthreads();
}

// =================== THE persistent kernel (plain launch + sw barrier) ===================
__global__ __launch_bounds__(256, 1) void decoder_loop(DecArgs p)
{
  __shared__ __align__(16) float smem[12928];   // 51.7 KB, unioned across phases
  const int bk = blockIdx.x;
  const int u0 = bk * 4;
  unsigned phase = 0;
  unsigned* cnt = p.bar_cnt;
  unsigned* rel = p.bar_rel;

  for (int t = 0; t < TMEL; ++t) {
    const float* ahT_rd  = p.ahT  + ((t+1)&1)*32768;
    float*       ahT_wr  = p.ahT  + (t&1)*32768;
    const float* dhT_rd  = p.dhT  + ((t+1)&1)*32768;
    float*       dhT_wr  = p.dhT  + (t&1)*32768;
    const float* awc_old = p.awcb + ((t+1)&1)*12800;
    float*       awc_new = p.awcb + (t&1)*12800;
    float*       ctx_cur = p.ctx2 + (t&1)*24576;
    const float* ctx_prev= p.ctx2 + ((t+1)&1)*24576;

    // P1: att-GEMM + fused att-cell  (ah(t), ac(t))
    gemm_cell(u0, p.xsT + (size_t)t*8192, 1, p.ctxT, 3, ahT_rd, 4,
              p.awih, 1024, p.awhh, p.abih, p.abhh,
              p.acT, ahT_wr, nullptr, smem);
    gbar(cnt, rel, ++phase);

    // P2: energies (with per-block pq)
    energies_phase(bk, p, ahT_wr, awc_old, smem);
    gbar(cnt, rel, ++phase);

    // P3: softmax + ctx (192 blocks) || proj(t-1) (16 blocks)
    if (bk < 192) {
      softmax_ctx_phase(bk, t, p, awc_old, awc_new, ctx_cur, smem);
    } else if (bk < 208) {
      if (t > 0) {
        int d = (bk - 192)*256 + threadIdx.x;
        proj_task(d, p.dh, ctx_prev, p.pw, p.pb, p.gw, p.gb,
                  p.out_mel, p.out_gate, t-1);
      }
    }
    gbar(cnt, rel, ++phase);

    // P4: dec-GEMM + fused dec-cell  (dh(t), dc(t))
    gemm_cell(u0, ahT_wr, 4, p.ctxT, 3, dhT_rd, 4,
              p.dwih, 1792, p.dwhh, p.dbih, p.dbhh,
              p.dcT, dhT_wr, p.dh, smem);
    gbar(cnt, rel, ++phase);
  }

  // final projection for t = TMEL-1
  if (bk >= 192 && bk < 208) {
    int d = (bk - 192)*256 + threadIdx.x;
    proj_task(d, p.dh, p.ctx2 + ((TMEL-1)&1)*24576, p.pw, p.pb, p.gw, p.gb,
              p.out_mel, p.out_gate, TMEL-1);
  }
}

extern "C" void kernel_launch(void* const* d_in, const int* in_sizes, int n_in,
                              void* d_out, int out_size, void* d_ws, size_t ws_size,
                              hipStream_t stream)
{
  const float* memory = (const float*)d_in[0];
  const float* din    = (const float*)d_in[1];
  const float* w1     = (const float*)d_in[3];
  const float* w2     = (const float*)d_in[4];
  const float* awih   = (const float*)d_in[5];
  const float* awhh   = (const float*)d_in[6];
  const float* abih   = (const float*)d_in[7];
  const float* abhh   = (const float*)d_in[8];
  const float* q_w    = (const float*)d_in[9];
  const float* mem_w  = (const float*)d_in[10];
  const float* v_w    = (const float*)d_in[11];
  const float* cw     = (const float*)d_in[12];
  const float* ldw    = (const float*)d_in[13];
  const float* dwih   = (const float*)d_in[14];
  const float* dwhh   = (const float*)d_in[15];
  const float* dbih   = (const float*)d_in[16];
  const float* dbhh   = (const float*)d_in[17];
  const float* pw     = (const float*)d_in[18];
  const float* pb     = (const float*)d_in[19];
  const float* gw     = (const float*)d_in[20];
  const float* gb     = (const float*)d_in[21];
  const int*   mlen   = (const int*)d_in[22];

  float* p = (float*)d_ws;
  float* xsT   = p;  p += 800*256*32;
  float* pmem  = p;  p += 32*400*128;
  float* qwT   = p;  p += 1024*128;
  // ---- zeroed state block ----
  float* zs    = p;
  float* barf  = p;  p += 64;             // barrier words (cnt @0, rel @32)
  float* ahT   = p;  p += 2*1024*32;
  float* dhT   = p;  p += 2*1024*32;
  float* dh    = p;  p += 32*1024;
  float* ctxT  = p;  p += 768*32;
  float* ctx2  = p;  p += 2*32*768;
  float* acT   = p;  p += 1024*32;
  float* dcT   = p;  p += 1024*32;
  float* aw    = p;  p += 32*400;
  float* awcb  = p;  p += 2*32*400;
  size_t zcount = (size_t)(p - zs);
  // ---- end zero block ----
  float* e     = p;  p += 32*400;

  float* out_mel   = (float*)d_out;
  float* out_gate  = out_mel + 32*80*800;
  float* out_align = out_gate + 32*800;

  hipMemsetAsync(zs, 0, zcount*sizeof(float), stream);
  prenet_kernel<<<TMEL, 256, 0, stream>>>(din, w1, w2, xsT);
  pmem_kernel<<<dim3(25,32), 256, 0, stream>>>(memory, mem_w, pmem);
  qwt_kernel<<<128, 256, 0, stream>>>(q_w, qwT);

  DecArgs a;
  a.xsT = xsT; a.pmem = pmem; a.qwT = qwT;
  a.awih = awih; a.awhh = awhh; a.abih = abih; a.abhh = abhh;
  a.dwih = dwih; a.dwhh = dwhh; a.dbih = dbih; a.dbhh = dbhh;
  a.cw = cw; a.ldw = ldw; a.vw = v_w; a.mlen = mlen;
  a.pw = pw; a.pb = pb; a.gw = gw; a.gb = gb;
  a.ahT = ahT; a.acT = acT; a.dhT = dhT; a.dh = dh; a.dcT = dcT;
  a.ctxT = ctxT; a.ctx2 = ctx2; a.aw = aw; a.awcb = awcb; a.e = e;
  a.memory = memory;
  a.out_mel = out_mel; a.out_gate = out_gate; a.out_align = out_align;
  a.bar_cnt = (unsigned*)barf;
  a.bar_rel = (unsigned*)barf + 32;

  decoder_loop<<<NBLK, 256, 0, stream>>>(a);
}

// Round 10
// 261075.244 us; speedup vs baseline: 1.2668x; 1.2668x over previous
//
#include <hip/hip_runtime.h>
#include <hip/hip_fp16.h>
#include <math.h>

#define TENC 400
#define TMEL 800
#define NMEL 80
#define ENCD 768
#define PRE  256
#define ARNN 1024
#define DRNN 1024
#define ATTD 128
#define NBLK 256

__device__ __forceinline__ float4 ld4(const float* p){ return *(const float4*)p; }
__device__ __forceinline__ float dot4(float4 a, float4 b){
  return a.x*b.x + a.y*b.y + a.z*b.z + a.w*b.w;
}
__device__ __forceinline__ float sigmf(float x){ return 1.f/(1.f + __expf(-x)); }

// =================== tree grid barrier (split fences) ===================
// leaf[8] (one per bk&7, 128B apart), root, rel. All zeroed per call, monotonic.
__device__ __forceinline__ void gbar(unsigned* bar, unsigned phase, int bk)
{
  __syncthreads();
  if (threadIdx.x == 0) {
    __builtin_amdgcn_fence(__ATOMIC_RELEASE, "agent");      // wbl2: publish writes
    unsigned* leaf = bar + (bk & 7) * 32;
    unsigned* root = bar + 256;
    unsigned* rel  = bar + 288;
    unsigned a = __hip_atomic_fetch_add(leaf, 1u, __ATOMIC_RELAXED,
                                        __HIP_MEMORY_SCOPE_AGENT) + 1u;
    if (a == phase * 32u) {
      unsigned r = __hip_atomic_fetch_add(root, 1u, __ATOMIC_RELAXED,
                                          __HIP_MEMORY_SCOPE_AGENT) + 1u;
      if (r == phase * 8u)
        __hip_atomic_store(rel, phase, __ATOMIC_RELAXED, __HIP_MEMORY_SCOPE_AGENT);
    }
    while (__hip_atomic_load(bar + 288, __ATOMIC_RELAXED,
                             __HIP_MEMORY_SCOPE_AGENT) < phase)
      __builtin_amdgcn_s_sleep(8);
    __builtin_amdgcn_fence(__ATOMIC_ACQUIRE, "agent");      // inv: see others' writes
  }
  __syncthreads();
}

// =================== prenet: xsT[t][k=256][b=32] ===================
__global__ __launch_bounds__(256) void prenet_kernel(
    const float* __restrict__ din, const float* __restrict__ w1,
    const float* __restrict__ w2, float* __restrict__ xsT)
{
  int t = blockIdx.x;
  __shared__ float f_s[32*80];
  __shared__ float p_s[32*257];
  for (int id = threadIdx.x; id < 32*80; id += 256) {
    int b = id / 80, m = id - b*80;
    f_s[id] = (t == 0) ? 0.f : din[b*(NMEL*TMEL) + m*TMEL + (t-1)];
  }
  __syncthreads();
  for (int b = 0; b < 32; ++b) {
    int k = threadIdx.x;
    float acc = 0.f;
    #pragma unroll 4
    for (int m = 0; m < 80; ++m) acc += f_s[b*80+m] * w1[k*80+m];
    p_s[b*257+k] = fmaxf(acc, 0.f);
  }
  __syncthreads();
  int b = threadIdx.x & 31, jslot = threadIdx.x >> 5;
  for (int jj = 0; jj < 32; ++jj) {
    int j = jslot*32 + jj;
    const float* w2r = w2 + j*256;
    float acc = 0.f;
    #pragma unroll 4
    for (int kk = 0; kk < 256; ++kk) acc += p_s[b*257+kk] * w2r[kk];
    xsT[(size_t)t*8192 + j*32 + b] = fmaxf(acc, 0.f);
  }
}

// =================== pmem16[b][t][128] (fp16 out) ===================
__global__ __launch_bounds__(256) void pmem_kernel(
  const float* __restrict__ mem, const float* __restrict__ mw, __half* __restrict__ pm16)
{
  int b = blockIdx.y, tc = blockIdx.x;
  int a = threadIdx.x & 127, th = threadIdx.x >> 7;
  for (int i = 0; i < 8; ++i) {
    int tt = tc*16 + th + 2*i;
    const float* mrow = mem + (size_t)b*(TENC*ENCD) + (size_t)tt*ENCD;
    const float* wrow = mw + a*ENCD;
    float acc = 0.f;
    #pragma unroll 4
    for (int e4 = 0; e4 < ENCD; e4 += 4) acc += dot4(ld4(mrow+e4), ld4(wrow+e4));
    pm16[b*(TENC*ATTD) + tt*ATTD + a] = __float2half(acc);
  }
}

// =================== qwT16[k=1024][a=128] (fp16) ===================
__global__ __launch_bounds__(256) void qwt_kernel(
  const float* __restrict__ qw, __half* __restrict__ qwT16)
{
  int a = blockIdx.x;
  for (int i = 0; i < 4; ++i) {
    int k = threadIdx.x + i*256;
    qwT16[k*128 + a] = __float2half(qw[a*1024 + k]);
  }
}

// =================== fp32 -> fp16 weight convert ===================
__global__ __launch_bounds__(256) void cvt16_kernel(
  const float* __restrict__ src, __half* __restrict__ dst, int n)
{
  int i = blockIdx.x*256 + threadIdx.x;
  int st = gridDim.x*256;
  for (; i < n; i += st) dst[i] = __float2half(src[i]);
}

// =================== args struct ===================
struct DecArgs {
  const float *xsT;
  const __half *awih16, *awhh16, *dwih16, *dwhh16, *qwT16, *pm16;
  const float *abih, *abhh, *dbih, *dbhh;
  const float *cw, *ldw, *vw;
  const int*  mlen;
  const float *pw, *pb, *gw, *gb;
  float *ahT, *acT, *dhT, *dh, *dcT;
  float *ctxT, *ctx2, *aw, *awcb, *e, *pq;
  const float *memory;
  float *out_mel, *out_gate, *out_align;
  unsigned *bar;
};

// =================== pipelined GEMM + fused cell (fp16 W, Kc=128) ===================
// Block owns u in [u0,u0+4): 16 staged rows = 4 gates x 4 u (validated r9 perm).
__device__ __forceinline__ void gemm_cell(int u0,
  const float* __restrict__ xtA, int cA, const float* __restrict__ xtB, int cB,
  const float* __restrict__ xtC, int cC,
  const __half* __restrict__ wih, int kih, const __half* __restrict__ whh,
  const float* __restrict__ bih, const float* __restrict__ bhh,
  float* __restrict__ cT, float* __restrict__ hT_out, float* __restrict__ h_row,
  float* smem)
{
  float4* Xs = (float4*)smem;          // 2 x 1024 float4
  float*  Ws = smem + 8192;            // 2 x (16*132)
  float*  G  = smem + 12416;           // 16*32
  const int tid = threadIdx.x;
  const int wave = tid >> 6, lane = tid & 63;
  const int klane = lane & 31, hlf = lane >> 5;
  const int tile = wave*2 + hlf;
  const int bg = tile & 3, rg = tile >> 2;
  const int b0 = bg*8, r0 = rg*8;
  float acc[8][8];
  #pragma unroll
  for (int i = 0; i < 8; ++i)
    #pragma unroll
    for (int j = 0; j < 8; ++j) acc[i][j] = 0.f;

  const int scol = tid & 7, skr = tid >> 3;       // X: k = skr+32i, i<4
  const int swr = tid >> 4, skk = (tid & 15)*8;   // W: 16 rows x 8 halfs
  const int jrow = ((swr >> 2)*1024) + u0 + (swr & 3);
  const int nC = cA + cB + cC;

  float4 xv0, xv1, xv2, xv3; uint4 wv;
  #define LOADC(c) { \
    const float* xsrc; int ck; \
    if ((c) < cA)            { xsrc = xtA; ck = (c); } \
    else if ((c) < cA + cB)  { xsrc = xtB; ck = (c) - cA; } \
    else                     { xsrc = xtC; ck = (c) - cA - cB; } \
    const float* xb_ = xsrc + (size_t)(ck*128)*32 + scol*4; \
    xv0 = *(const float4*)(xb_ + (size_t)(skr      )*32); \
    xv1 = *(const float4*)(xb_ + (size_t)(skr +  32)*32); \
    xv2 = *(const float4*)(xb_ + (size_t)(skr +  64)*32); \
    xv3 = *(const float4*)(xb_ + (size_t)(skr +  96)*32); \
    int kglob = (c)*128 + skk; \
    const __half* wr = (kglob < kih) ? (wih + (size_t)jrow*kih + kglob) \
                                     : (whh + (size_t)jrow*1024 + (kglob - kih)); \
    wv = *(const uint4*)wr; }

  LOADC(0);
  for (int c = 0; c < nC; ++c) {
    int bsel = c & 1;
    float4* Xb = Xs + bsel*1024;
    float*  Wb = Ws + bsel*2112;
    { int k;
      k = skr;      Xb[k*8 + (scol ^ (k & 7))] = xv0;
      k = skr + 32; Xb[k*8 + (scol ^ (k & 7))] = xv1;
      k = skr + 64; Xb[k*8 + (scol ^ (k & 7))] = xv2;
      k = skr + 96; Xb[k*8 + (scol ^ (k & 7))] = xv3; }
    { const __half* h = (const __half*)&wv;
      float* wd = Wb + swr*132 + skk;
      #pragma unroll
      for (int q = 0; q < 8; ++q) wd[q] = __half2float(h[q]); }
    __syncthreads();
    if (c + 1 < nC) LOADC(c + 1);        // loads fly during compute
    #pragma unroll
    for (int kk = 0; kk < 4; ++kk) {
      int k = klane + 32*kk;
      float4 x0 = Xb[k*8 + ((bg*2)     ^ (klane & 7))];
      float4 x1 = Xb[k*8 + ((bg*2 + 1) ^ (klane & 7))];
      float w[8];
      #pragma unroll
      for (int r = 0; r < 8; ++r) w[r] = Wb[(r0 + r)*132 + k];
      float xb[8] = {x0.x, x0.y, x0.z, x0.w, x1.x, x1.y, x1.z, x1.w};
      #pragma unroll
      for (int r = 0; r < 8; ++r)
        #pragma unroll
        for (int bb = 0; bb < 8; ++bb)
          acc[bb][r] += xb[bb] * w[r];
    }
  }
  #undef LOADC
  #pragma unroll
  for (int m = 16; m >= 1; m >>= 1)
    #pragma unroll
    for (int bb = 0; bb < 8; ++bb)
      #pragma unroll
      for (int r = 0; r < 8; ++r)
        acc[bb][r] += __shfl_xor(acc[bb][r], m);
  __syncthreads();                      // all compute done before G write region reuse
  if (klane == 0) {
    #pragma unroll
    for (int r = 0; r < 8; ++r) {
      float4 lo = make_float4(acc[0][r], acc[1][r], acc[2][r], acc[3][r]);
      float4 hi = make_float4(acc[4][r], acc[5][r], acc[6][r], acc[7][r]);
      *(float4*)(G + (r0 + r)*32 + b0)     = lo;
      *(float4*)(G + (r0 + r)*32 + b0 + 4) = hi;
    }
  }
  __syncthreads();
  if (tid < 128) {
    int du = tid >> 5, b = tid & 31;
    int u = u0 + du;
    float gi = G[(0*4+du)*32 + b] + bih[u]      + bhh[u];
    float gf = G[(1*4+du)*32 + b] + bih[1024+u] + bhh[1024+u];
    float gg = G[(2*4+du)*32 + b] + bih[2048+u] + bhh[2048+u];
    float go = G[(3*4+du)*32 + b] + bih[3072+u] + bhh[3072+u];
    float c  = cT[u*32 + b];
    float cn = sigmf(gf)*c + sigmf(gi)*tanhf(gg);
    float h  = sigmf(go)*tanhf(cn);
    cT[u*32 + b]     = cn;
    hT_out[u*32 + b] = h;
    if (h_row) h_row[b*1024 + u] = h;
  }
  __syncthreads();
}

// =================== projection helper ===================
__device__ __forceinline__ void proj_task(int d, const float* dh, const float* ctx,
    const float* proj_w, const float* proj_b, const float* gate_w, const float* gate_b,
    float* out_mel, float* out_gate, int t)
{
  if (d >= 32*81) return;
  int b = d / 81, r = d - b*81;
  const float* w   = (r < 80) ? (proj_w + r*1792) : gate_w;
  const float* dhr = dh + b*DRNN;
  const float* cxr = ctx + b*ENCD;
  float acc = 0.f;
  #pragma unroll 4
  for (int k = 0; k < 1024; k += 4) acc += dot4(ld4(dhr+k), ld4(w+k));
  #pragma unroll 4
  for (int k = 0; k < 768;  k += 4) acc += dot4(ld4(cxr+k), ld4(w+1024+k));
  if (r < 80) out_mel[(b*80 + r)*TMEL + t] = acc + proj_b[r];
  else        out_gate[b*TMEL + t]         = acc + gate_b[0];
}

// =================== P2: pq (32 blocks) ===================
__device__ __forceinline__ void pq_phase(int b, const DecArgs& p,
  const float* ahT_cur, float* smem)
{
  float* ah_s = smem;          // 1024
  float* part = smem + 1024;   // 256
  int tid = threadIdx.x;
  for (int u = tid; u < 1024; u += 256) ah_s[u] = ahT_cur[u*32 + b];
  __syncthreads();
  int a = tid & 127, kh = tid >> 7;
  float acc = 0.f;
  for (int k = kh*512; k < kh*512 + 512; ++k)
    acc += ah_s[k] * __half2float(p.qwT16[k*128 + a]);
  part[tid] = acc;
  __syncthreads();
  if (tid < 128) p.pq[b*128 + tid] = part[tid] + part[tid + 128];
}

// =================== P3: energies (256 blocks) ===================
__device__ __forceinline__ void energies_phase(int bk, const DecArgs& p,
  const float* awc_old, float* smem)
{
  int b = bk >> 3, c8 = bk & 7, t0 = c8 * 50;
  float* pq_s  = smem;         // 128
  float* aw_s  = smem + 128;   // 80
  float* awc_s = smem + 208;   // 80
  float* loc_s = smem + 288;   // 50*33
  float* epart = smem + 1938;  // 50*4
  int tid = threadIdx.x;
  if (tid < 128) pq_s[tid] = p.pq[b*128 + tid];
  if (tid >= 96) {             // 160 loader threads -> i in [0,160)
    int i = tid - 96;
    int h = (i < 80) ? i : i - 80;
    bool isC = i >= 80;
    int g = t0 - 15 + h;
    float v = (g >= 0 && g < TENC) ? (isC ? awc_old[b*TENC+g] : p.aw[b*TENC+g]) : 0.f;
    if (isC) awc_s[h] = v; else aw_s[h] = v;
  }
  __syncthreads();
  for (int id = tid; id < 50*32; id += 256) {
    int tl = id >> 5, f = id & 31;
    const float* w0 = p.cw + f*62;
    float acc = 0.f;
    #pragma unroll
    for (int k = 0; k < 31; ++k)
      acc += aw_s[tl+k]*w0[k] + awc_s[tl+k]*w0[31+k];
    loc_s[tl*33 + f] = acc;
  }
  __syncthreads();
  if (tid < 200) {
    int tl = tid >> 2, qa = tid & 3;
    int tt = t0 + tl;
    const __half* pm = p.pm16 + b*(TENC*ATTD) + tt*ATTD;
    float s = 0.f;
    for (int a = qa*32; a < qa*32 + 32; ++a) {
      const float* lw = p.ldw + a*32;
      float pl = 0.f;
      #pragma unroll 8
      for (int f = 0; f < 32; ++f) pl += loc_s[tl*33 + f] * lw[f];
      s += p.vw[a] * tanhf(pq_s[a] + __half2float(pm[a]) + pl);
    }
    epart[tl*4 + qa] = s;
  }
  __syncthreads();
  if (tid < 50) {
    int tt = t0 + tid;
    float v = epart[tid*4] + epart[tid*4+1] + epart[tid*4+2] + epart[tid*4+3];
    if (tt >= p.mlen[b]) v = -1000000000.0f;
    p.e[b*TENC + tt] = v;
  }
  __syncthreads();
}

// =================== P4: softmax + LDS-resident ctx (+proj subset) ===================
__device__ __forceinline__ void sm_ctx_phase(int bk, int t, const DecArgs& p,
  const float* awc_old, float* awc_new, float* ctx_cur, const __half2* mem_s,
  float* smem)
{
  int b = bk >> 3, jc = bk & 7, j0 = jc*96;
  int tid = threadIdx.x;
  float* red   = smem;         // 256
  float* aw_s  = smem + 256;   // 400
  float* cpart = smem + 656;   // 384
  float v0 = p.e[b*TENC + tid];
  float v1 = (tid + 256 < TENC) ? p.e[b*TENC + tid + 256] : -3.0e38f;
  red[tid] = fmaxf(v0, v1); __syncthreads();
  for (int s = 128; s > 0; s >>= 1) {
    if (tid < s) red[tid] = fmaxf(red[tid], red[tid+s]);
    __syncthreads();
  }
  float mx = red[0]; __syncthreads();
  float p0 = __expf(v0 - mx);
  float p1 = (tid + 256 < TENC) ? __expf(v1 - mx) : 0.f;
  red[tid] = p0 + p1; __syncthreads();
  for (int s = 128; s > 0; s >>= 1) {
    if (tid < s) red[tid] += red[tid+s];
    __syncthreads();
  }
  float inv = 1.f / red[0];
  aw_s[tid] = p0 * inv;
  if (tid + 256 < TENC) aw_s[tid + 256] = p1 * inv;
  __syncthreads();
  // ctx slice from LDS memory (96 j's per block, as 48 half2 pairs)
  if (tid < 192) {
    int jp = tid % 48, h = tid / 48;
    float ax = 0.f, ay = 0.f;
    for (int tt = h*100; tt < h*100 + 100; ++tt) {
      float av = aw_s[tt];
      float2 m = __half22float2(mem_s[tt*48 + jp]);
      ax += av * m.x; ay += av * m.y;
    }
    cpart[(h*48 + jp)*2]     = ax;
    cpart[(h*48 + jp)*2 + 1] = ay;
  }
  __syncthreads();
  if (tid < 48) {
    float sx = cpart[tid*2]        + cpart[(48+tid)*2]
             + cpart[(96+tid)*2]   + cpart[(144+tid)*2];
    float sy = cpart[tid*2+1]      + cpart[(48+tid)*2+1]
             + cpart[(96+tid)*2+1] + cpart[(144+tid)*2+1];
    int j = j0 + tid*2;
    p.ctxT[(size_t)j*32 + b]     = sx;
    p.ctxT[(size_t)(j+1)*32 + b] = sy;
    ctx_cur[b*ENCD + j]     = sx;
    ctx_cur[b*ENCD + j + 1] = sy;
  }
  if (jc == 0) {
    for (int i = tid; i < TENC; i += 256) {
      float a = aw_s[i];
      p.aw[b*TENC + i] = a;
      awc_new[b*TENC + i] = awc_old[b*TENC + i] + a;
      p.out_align[((size_t)b*TMEL + t)*TENC + i] = a;
    }
  }
  __syncthreads();
}

// =================== THE persistent kernel ===================
__global__ __launch_bounds__(256, 1) void decoder_loop(DecArgs p)
{
  __shared__ __align__(16) float scratch[12928];   // 51.7 KB (union)
  __shared__ __half2 mem_s[400*48];                // 76.8 KB (persistent)
  const int bk = blockIdx.x;
  const int u0 = bk * 4;
  unsigned phase = 0;

  // preload this block's memory slice (b = bk>>3, cols j0..j0+95) as fp16
  {
    int b = bk >> 3, jc = bk & 7, j0 = jc*96;
    const float* mb = p.memory + (size_t)b*(TENC*ENCD);
    for (int idx = threadIdx.x; idx < 400*48; idx += 256) {
      int tt = idx / 48, jp = idx - tt*48;
      float m0 = mb[(size_t)tt*ENCD + j0 + jp*2];
      float m1 = mb[(size_t)tt*ENCD + j0 + jp*2 + 1];
      mem_s[idx] = __floats2half2_rn(m0, m1);
    }
  }
  __syncthreads();

  for (int t = 0; t < TMEL; ++t) {
    const float* ahT_rd  = p.ahT  + ((t+1)&1)*32768;
    float*       ahT_wr  = p.ahT  + (t&1)*32768;
    const float* dhT_rd  = p.dhT  + ((t+1)&1)*32768;
    float*       dhT_wr  = p.dhT  + (t&1)*32768;
    const float* awc_old = p.awcb + ((t+1)&1)*12800;
    float*       awc_new = p.awcb + (t&1)*12800;
    float*       ctx_cur = p.ctx2 + (t&1)*24576;
    const float* ctx_prev= p.ctx2 + ((t+1)&1)*24576;

    // P1: att-GEMM + cell
    gemm_cell(u0, p.xsT + (size_t)t*8192, 2, p.ctxT, 6, ahT_rd, 8,
              p.awih16, 1024, p.awhh16, p.abih, p.abhh,
              p.acT, ahT_wr, nullptr, scratch);
    gbar(p.bar, ++phase, bk);

    // P2: pq (32 blocks)
    if (bk < 32) pq_phase(bk, p, ahT_wr, scratch);
    gbar(p.bar, ++phase, bk);

    // P3: energies
    energies_phase(bk, p, awc_old, scratch);
    gbar(p.bar, ++phase, bk);

    // P4: softmax + ctx (all blocks) + proj(t-1) (16 blocks)
    sm_ctx_phase(bk, t, p, awc_old, awc_new, ctx_cur, mem_s, scratch);
    if ((bk & 7) == 7 && (bk >> 3) < 16 && t > 0) {
      int d = (bk >> 3)*256 + threadIdx.x;
      proj_task(d, p.dh, ctx_prev, p.pw, p.pb, p.gw, p.gb,
                p.out_mel, p.out_gate, t-1);
    }
    gbar(p.bar, ++phase, bk);

    // P5: dec-GEMM + cell
    gemm_cell(u0, ahT_wr, 8, p.ctxT, 6, dhT_rd, 8,
              p.dwih16, 1792, p.dwhh16, p.dbih, p.dbhh,
              p.dcT, dhT_wr, p.dh, scratch);
    gbar(p.bar, ++phase, bk);
  }

  // final projection (t = TMEL-1)
  if ((bk & 7) == 7 && (bk >> 3) < 16) {
    int d = (bk >> 3)*256 + threadIdx.x;
    proj_task(d, p.dh, p.ctx2 + ((TMEL-1)&1)*24576, p.pw, p.pb, p.gw, p.gb,
              p.out_mel, p.out_gate, TMEL-1);
  }
}

extern "C" void kernel_launch(void* const* d_in, const int* in_sizes, int n_in,
                              void* d_out, int out_size, void* d_ws, size_t ws_size,
                              hipStream_t stream)
{
  const float* memory = (const float*)d_in[0];
  const float* din    = (const float*)d_in[1];
  const float* w1     = (const float*)d_in[3];
  const float* w2     = (const float*)d_in[4];
  const float* awih   = (const float*)d_in[5];
  const float* awhh   = (const float*)d_in[6];
  const float* abih   = (const float*)d_in[7];
  const float* abhh   = (const float*)d_in[8];
  const float* q_w    = (const float*)d_in[9];
  const float* mem_w  = (const float*)d_in[10];
  const float* v_w    = (const float*)d_in[11];
  const float* cw     = (const float*)d_in[12];
  const float* ldw    = (const float*)d_in[13];
  const float* dwih   = (const float*)d_in[14];
  const float* dwhh   = (const float*)d_in[15];
  const float* dbih   = (const float*)d_in[16];
  const float* dbhh   = (const float*)d_in[17];
  const float* pw     = (const float*)d_in[18];
  const float* pb     = (const float*)d_in[19];
  const float* gw     = (const float*)d_in[20];
  const float* gb     = (const float*)d_in[21];
  const int*   mlen   = (const int*)d_in[22];

  float* p = (float*)d_ws;
  float* xsT    = p;              p += 800*256*32;   // 6,553,600
  __half* awih16 = (__half*)p;    p += 2097152;      // 4096x1024 halfs
  __half* awhh16 = (__half*)p;    p += 2097152;
  __half* dwih16 = (__half*)p;    p += 3670016;      // 4096x1792 halfs
  __half* dwhh16 = (__half*)p;    p += 2097152;
  __half* qwT16  = (__half*)p;    p += 65536;        // 1024x128 halfs
  __half* pm16   = (__half*)p;    p += 819200;       // 32x400x128 halfs
  // ---- zeroed state block ----
  float* zs    = p;
  unsigned* bar = (unsigned*)p;   p += 320;          // tree barrier words
  float* ahT   = p;  p += 2*1024*32;
  float* dhT   = p;  p += 2*1024*32;
  float* dh    = p;  p += 32*1024;
  float* ctxT  = p;  p += 768*32;
  float* ctx2  = p;  p += 2*32*768;
  float* acT   = p;  p += 1024*32;
  float* dcT   = p;  p += 1024*32;
  float* aw    = p;  p += 32*400;
  float* awcb  = p;  p += 2*32*400;
  size_t zcount = (size_t)(p - zs);
  // ---- end zero block ----
  float* e     = p;  p += 32*400;
  float* pq    = p;  p += 32*128;

  float* out_mel   = (float*)d_out;
  float* out_gate  = out_mel + 32*80*800;
  float* out_align = out_gate + 32*800;

  hipMemsetAsync(zs, 0, zcount*sizeof(float), stream);
  prenet_kernel<<<TMEL, 256, 0, stream>>>(din, w1, w2, xsT);
  pmem_kernel<<<dim3(25,32), 256, 0, stream>>>(memory, mem_w, pm16);
  qwt_kernel<<<128, 256, 0, stream>>>(q_w, qwT16);
  cvt16_kernel<<<2048, 256, 0, stream>>>(awih, awih16, 4096*1024);
  cvt16_kernel<<<2048, 256, 0, stream>>>(awhh, awhh16, 4096*1024);
  cvt16_kernel<<<2048, 256, 0, stream>>>(dwih, dwih16, 4096*1792);
  cvt16_kernel<<<2048, 256, 0, stream>>>(dwhh, dwhh16, 4096*1024);

  DecArgs a;
  a.xsT = xsT;
  a.awih16 = awih16; a.awhh16 = awhh16; a.dwih16 = dwih16; a.dwhh16 = dwhh16;
  a.qwT16 = qwT16; a.pm16 = pm16;
  a.abih = abih; a.abhh = abhh; a.dbih = dbih; a.dbhh = dbhh;
  a.cw = cw; a.ldw = ldw; a.vw = v_w; a.mlen = mlen;
  a.pw = pw; a.pb = pb; a.gw = gw; a.gb = gb;
  a.ahT = ahT; a.acT = acT; a.dhT = dhT; a.dh = dh; a.dcT = dcT;
  a.ctxT = ctxT; a.ctx2 = ctx2; a.aw = aw; a.awcb = awcb; a.e = e; a.pq = pq;
  a.memory = memory;
  a.out_mel = out_mel; a.out_gate = out_gate; a.out_align = out_align;
  a.bar = bar;

  decoder_loop<<<NBLK, 256, 0, stream>>>(a);
}

// Round 11
// 193667.236 us; speedup vs baseline: 1.7077x; 1.3481x over previous
//
#include <hip/hip_runtime.h>
#include <hip/hip_fp16.h>
#include <math.h>

#define TENC 400
#define TMEL 800
#define NMEL 80
#define ENCD 768
#define PRE  256
#define ARNN 1024
#define DRNN 1024
#define ATTD 128
#define NBLK 256

__device__ __forceinline__ float4 ld4(const float* p){ return *(const float4*)p; }
__device__ __forceinline__ float dot4(float4 a, float4 b){
  return a.x*b.x + a.y*b.y + a.z*b.z + a.w*b.w;
}
__device__ __forceinline__ float sigmf(float x){ return 1.f/(1.f + __expf(-x)); }

// ---- coherent (agent-scope, cache-bypassing) accessors for mutable shared state ----
__device__ __forceinline__ float ld_c(const float* p){
  union { unsigned u; float f; } c;
  c.u = __hip_atomic_load((const unsigned*)p, __ATOMIC_RELAXED, __HIP_MEMORY_SCOPE_AGENT);
  return c.f;
}
__device__ __forceinline__ void st_c(float* p, float v){
  union { unsigned u; float f; } c; c.f = v;
  __hip_atomic_store((unsigned*)p, c.u, __ATOMIC_RELAXED, __HIP_MEMORY_SCOPE_AGENT);
}
__device__ __forceinline__ float2 ld2_c(const float* p){
  union { unsigned long long u; float2 f; } c;
  c.u = __hip_atomic_load((const unsigned long long*)p, __ATOMIC_RELAXED,
                          __HIP_MEMORY_SCOPE_AGENT);
  return c.f;
}
__device__ __forceinline__ float4 ld4_c(const float* p){
  union { unsigned long long u[2]; float4 f; } c;
  c.u[0] = __hip_atomic_load((const unsigned long long*)p, __ATOMIC_RELAXED,
                             __HIP_MEMORY_SCOPE_AGENT);
  c.u[1] = __hip_atomic_load((const unsigned long long*)(p+2), __ATOMIC_RELAXED,
                             __HIP_MEMORY_SCOPE_AGENT);
  return c.f;
}

// =================== fence-free tree grid barrier ===================
// All relaxed agent atomics; producer drains its coherent stores with vmcnt(0);
// NO buffer_inv / buffer_wbl2 -> L2-cached weights survive across phases.
__device__ __forceinline__ void gbar(unsigned* bar, unsigned phase, int bk)
{
  __syncthreads();
  if (threadIdx.x == 0) {
    asm volatile("s_waitcnt vmcnt(0)" ::: "memory");   // coherent stores complete
    unsigned* leaf = bar + (bk & 7) * 32;
    unsigned* root = bar + 256;
    unsigned* rel  = bar + 288;
    unsigned a = __hip_atomic_fetch_add(leaf, 1u, __ATOMIC_RELAXED,
                                        __HIP_MEMORY_SCOPE_AGENT) + 1u;
    if (a == phase * 32u) {
      unsigned r = __hip_atomic_fetch_add(root, 1u, __ATOMIC_RELAXED,
                                          __HIP_MEMORY_SCOPE_AGENT) + 1u;
      if (r == phase * 8u)
        __hip_atomic_store(rel, phase, __ATOMIC_RELAXED, __HIP_MEMORY_SCOPE_AGENT);
    }
    while (__hip_atomic_load(rel, __ATOMIC_RELAXED, __HIP_MEMORY_SCOPE_AGENT) < phase)
      __builtin_amdgcn_s_sleep(8);
    asm volatile("" ::: "memory");                     // no compiler reordering
  }
  __syncthreads();
}

// =================== prenet: xsT[t][k=256][b=32] ===================
__global__ __launch_bounds__(256) void prenet_kernel(
    const float* __restrict__ din, const float* __restrict__ w1,
    const float* __restrict__ w2, float* __restrict__ xsT)
{
  int t = blockIdx.x;
  __shared__ float f_s[32*80];
  __shared__ float p_s[32*257];
  for (int id = threadIdx.x; id < 32*80; id += 256) {
    int b = id / 80, m = id - b*80;
    f_s[id] = (t == 0) ? 0.f : din[b*(NMEL*TMEL) + m*TMEL + (t-1)];
  }
  __syncthreads();
  for (int b = 0; b < 32; ++b) {
    int k = threadIdx.x;
    float acc = 0.f;
    #pragma unroll 4
    for (int m = 0; m < 80; ++m) acc += f_s[b*80+m] * w1[k*80+m];
    p_s[b*257+k] = fmaxf(acc, 0.f);
  }
  __syncthreads();
  int b = threadIdx.x & 31, jslot = threadIdx.x >> 5;
  for (int jj = 0; jj < 32; ++jj) {
    int j = jslot*32 + jj;
    const float* w2r = w2 + j*256;
    float acc = 0.f;
    #pragma unroll 4
    for (int kk = 0; kk < 256; ++kk) acc += p_s[b*257+kk] * w2r[kk];
    xsT[(size_t)t*8192 + j*32 + b] = fmaxf(acc, 0.f);
  }
}

// =================== pmem16[b][t][128] (fp16) ===================
__global__ __launch_bounds__(256) void pmem_kernel(
  const float* __restrict__ mem, const float* __restrict__ mw, __half* __restrict__ pm16)
{
  int b = blockIdx.y, tc = blockIdx.x;
  int a = threadIdx.x & 127, th = threadIdx.x >> 7;
  for (int i = 0; i < 8; ++i) {
    int tt = tc*16 + th + 2*i;
    const float* mrow = mem + (size_t)b*(TENC*ENCD) + (size_t)tt*ENCD;
    const float* wrow = mw + a*ENCD;
    float acc = 0.f;
    #pragma unroll 4
    for (int e4 = 0; e4 < ENCD; e4 += 4) acc += dot4(ld4(mrow+e4), ld4(wrow+e4));
    pm16[b*(TENC*ATTD) + tt*ATTD + a] = __float2half(acc);
  }
}

// =================== fp32 -> fp16 convert ===================
__global__ __launch_bounds__(256) void cvt16_kernel(
  const float* __restrict__ src, __half* __restrict__ dst, int n)
{
  int i = blockIdx.x*256 + threadIdx.x;
  int st = gridDim.x*256;
  for (; i < n; i += st) dst[i] = __float2half(src[i]);
}

// =================== args struct ===================
struct DecArgs {
  const float *xsT;
  const __half *awih16, *awhh16, *dwih16, *dwhh16, *qw16, *pm16;
  const float *abih, *abhh, *dbih, *dbhh;
  const float *cw, *ldw, *vw;
  const int*  mlen;
  const float *pw, *pb, *gw, *gb;
  float *ahT, *acT, *dhT, *dh, *dcT, *ah_row;
  float *ctxT, *ctx2, *aw, *awcb, *e;
  const float *memory;
  float *out_mel, *out_gate, *out_align;
  unsigned *bar;
};

// =================== pipelined GEMM + fused cell (fp16 W, Kc=128) ===================
// Mutable X sources (ctxT/ahT/dhT) read coherently; weights/xsT cached.
__device__ __forceinline__ void gemm_cell(int u0, bool sA,
  const float* __restrict__ xtA, int cA, const float* __restrict__ xtB, int cB,
  const float* __restrict__ xtC, int cC,
  const __half* __restrict__ wih, int kih, const __half* __restrict__ whh,
  const float* __restrict__ bih, const float* __restrict__ bhh,
  float* __restrict__ cT, float* __restrict__ hT_out, float* __restrict__ h_row,
  float* smem)
{
  float4* Xs = (float4*)smem;          // 2 x 1024 float4
  float*  Ws = smem + 8192;            // 2 x (16*132)
  float*  G  = smem + 12416;           // 16*32
  const int tid = threadIdx.x;
  const int wave = tid >> 6, lane = tid & 63;
  const int klane = lane & 31, hlf = lane >> 5;
  const int tile = wave*2 + hlf;
  const int bg = tile & 3, rg = tile >> 2;
  const int b0 = bg*8, r0 = rg*8;
  float acc[8][8];
  #pragma unroll
  for (int i = 0; i < 8; ++i)
    #pragma unroll
    for (int j = 0; j < 8; ++j) acc[i][j] = 0.f;

  const int scol = tid & 7, skr = tid >> 3;
  const int swr = tid >> 4, skk = (tid & 15)*8;
  const int jrow = ((swr >> 2)*1024) + u0 + (swr & 3);
  const int nC = cA + cB + cC;

  float4 xv0, xv1, xv2, xv3; uint4 wv;
  #define LOADC(c) { \
    const float* xsrc; int ck; bool ssc; \
    if ((c) < cA)            { xsrc = xtA; ck = (c); ssc = sA; } \
    else if ((c) < cA + cB)  { xsrc = xtB; ck = (c) - cA; ssc = true; } \
    else                     { xsrc = xtC; ck = (c) - cA - cB; ssc = true; } \
    const float* xb_ = xsrc + (size_t)(ck*128)*32 + scol*4; \
    if (ssc) { \
      xv0 = ld4_c(xb_ + (size_t)(skr      )*32); \
      xv1 = ld4_c(xb_ + (size_t)(skr +  32)*32); \
      xv2 = ld4_c(xb_ + (size_t)(skr +  64)*32); \
      xv3 = ld4_c(xb_ + (size_t)(skr +  96)*32); \
    } else { \
      xv0 = *(const float4*)(xb_ + (size_t)(skr      )*32); \
      xv1 = *(const float4*)(xb_ + (size_t)(skr +  32)*32); \
      xv2 = *(const float4*)(xb_ + (size_t)(skr +  64)*32); \
      xv3 = *(const float4*)(xb_ + (size_t)(skr +  96)*32); \
    } \
    int kglob = (c)*128 + skk; \
    const __half* wr = (kglob < kih) ? (wih + (size_t)jrow*kih + kglob) \
                                     : (whh + (size_t)jrow*1024 + (kglob - kih)); \
    wv = *(const uint4*)wr; }

  LOADC(0);
  for (int c = 0; c < nC; ++c) {
    int bsel = c & 1;
    float4* Xb = Xs + bsel*1024;
    float*  Wb = Ws + bsel*2112;
    { int k;
      k = skr;      Xb[k*8 + (scol ^ (k & 7))] = xv0;
      k = skr + 32; Xb[k*8 + (scol ^ (k & 7))] = xv1;
      k = skr + 64; Xb[k*8 + (scol ^ (k & 7))] = xv2;
      k = skr + 96; Xb[k*8 + (scol ^ (k & 7))] = xv3; }
    { const __half* h = (const __half*)&wv;
      float* wd = Wb + swr*132 + skk;
      #pragma unroll
      for (int q = 0; q < 8; ++q) wd[q] = __half2float(h[q]); }
    __syncthreads();
    if (c + 1 < nC) LOADC(c + 1);        // prefetch flies during compute
    #pragma unroll
    for (int kk = 0; kk < 4; ++kk) {
      int k = klane + 32*kk;
      float4 x0 = Xb[k*8 + ((bg*2)     ^ (klane & 7))];
      float4 x1 = Xb[k*8 + ((bg*2 + 1) ^ (klane & 7))];
      float w[8];
      #pragma unroll
      for (int r = 0; r < 8; ++r) w[r] = Wb[(r0 + r)*132 + k];
      float xb[8] = {x0.x, x0.y, x0.z, x0.w, x1.x, x1.y, x1.z, x1.w};
      #pragma unroll
      for (int r = 0; r < 8; ++r)
        #pragma unroll
        for (int bb = 0; bb < 8; ++bb)
          acc[bb][r] += xb[bb] * w[r];
    }
  }
  #undef LOADC
  #pragma unroll
  for (int m = 16; m >= 1; m >>= 1)
    #pragma unroll
    for (int bb = 0; bb < 8; ++bb)
      #pragma unroll
      for (int r = 0; r < 8; ++r)
        acc[bb][r] += __shfl_xor(acc[bb][r], m);
  __syncthreads();
  if (klane == 0) {
    #pragma unroll
    for (int r = 0; r < 8; ++r) {
      float4 lo = make_float4(acc[0][r], acc[1][r], acc[2][r], acc[3][r]);
      float4 hi = make_float4(acc[4][r], acc[5][r], acc[6][r], acc[7][r]);
      *(float4*)(G + (r0 + r)*32 + b0)     = lo;
      *(float4*)(G + (r0 + r)*32 + b0 + 4) = hi;
    }
  }
  __syncthreads();
  if (tid < 128) {
    int du = tid >> 5, b = tid & 31;
    int u = u0 + du;
    float gi = G[(0*4+du)*32 + b] + bih[u]      + bhh[u];
    float gf = G[(1*4+du)*32 + b] + bih[1024+u] + bhh[1024+u];
    float gg = G[(2*4+du)*32 + b] + bih[2048+u] + bhh[2048+u];
    float go = G[(3*4+du)*32 + b] + bih[3072+u] + bhh[3072+u];
    float c  = cT[u*32 + b];                   // block-private: cached
    float cn = sigmf(gf)*c + sigmf(gi)*tanhf(gg);
    float h  = sigmf(go)*tanhf(cn);
    cT[u*32 + b] = cn;
    st_c(&hT_out[u*32 + b], h);
    if (h_row) st_c(&h_row[b*1024 + u], h);
  }
  __syncthreads();
}

// =================== projection helper (coherent dh/ctx reads) ===================
__device__ __forceinline__ void proj_task(int d, const float* dh, const float* ctx,
    const float* proj_w, const float* proj_b, const float* gate_w, const float* gate_b,
    float* out_mel, float* out_gate, int t)
{
  if (d >= 32*81) return;
  int b = d / 81, r = d - b*81;
  const float* w   = (r < 80) ? (proj_w + r*1792) : gate_w;
  const float* dhr = dh + b*DRNN;
  const float* cxr = ctx + b*ENCD;
  float acc = 0.f;
  for (int k = 0; k < 1024; k += 4) {
    float4 wv = ld4(w + k);
    float2 a0 = ld2_c(dhr + k), a1 = ld2_c(dhr + k + 2);
    acc += a0.x*wv.x + a0.y*wv.y + a1.x*wv.z + a1.y*wv.w;
  }
  for (int k = 0; k < 768; k += 4) {
    float4 wv = ld4(w + 1024 + k);
    float2 a0 = ld2_c(cxr + k), a1 = ld2_c(cxr + k + 2);
    acc += a0.x*wv.x + a0.y*wv.y + a1.x*wv.z + a1.y*wv.w;
  }
  if (r < 80) out_mel[(b*80 + r)*TMEL + t] = acc + proj_b[r];
  else        out_gate[b*TMEL + t]         = acc + gate_b[0];
}

// =================== P2: energies (+ folded pq) ===================
__device__ __forceinline__ void energies_phase(int bk, const DecArgs& p,
  const float* awc_old, float* smem)
{
  int b = bk >> 3, c8 = bk & 7, t0 = c8 * 50;
  float* ah_s  = smem;          // 1024
  float* pq_s  = smem + 1024;   // 128
  float* part  = smem + 1152;   // 256
  float* aw_s  = smem + 1408;   // 80
  float* awc_s = smem + 1488;   // 80
  float* loc_s = smem + 1568;   // 50*33
  float* epart = smem + 3218;   // 50*4
  int tid = threadIdx.x;
  { // ah row (coherent, coalesced 8B)
    float2 v0 = ld2_c(p.ah_row + b*1024 + tid*4);
    float2 v1 = ld2_c(p.ah_row + b*1024 + tid*4 + 2);
    ah_s[tid*4]   = v0.x; ah_s[tid*4+1] = v0.y;
    ah_s[tid*4+2] = v1.x; ah_s[tid*4+3] = v1.y;
  }
  if (tid >= 96) {              // halo: 160 threads -> i in [0,160)
    int i = tid - 96;
    int h = (i < 80) ? i : i - 80;
    bool isC = i >= 80;
    int g = t0 - 15 + h;
    float v = (g >= 0 && g < TENC)
            ? (isC ? ld_c(awc_old + b*TENC + g) : ld_c(p.aw + b*TENC + g)) : 0.f;
    if (isC) awc_s[h] = v; else aw_s[h] = v;
  }
  __syncthreads();
  { // pq[a] redundant per block (qw16 L2-cached, immutable)
    int a = tid & 127, kh = tid >> 7;
    const __half* qr = p.qw16 + (size_t)a*1024 + kh*512;
    const float*  ar = ah_s + kh*512;
    float acc = 0.f;
    for (int k = 0; k < 512; k += 8) {
      uint4 hv = *(const uint4*)(qr + k);
      const __half2* h2 = (const __half2*)&hv;
      #pragma unroll
      for (int q = 0; q < 4; ++q) {
        float2 wf = __half22float2(h2[q]);
        acc += ar[k + q*2]*wf.x + ar[k + q*2 + 1]*wf.y;
      }
    }
    part[tid] = acc;
  }
  // location conv (aw_s/awc_s ready)
  __syncthreads();
  if (tid < 128) pq_s[tid] = part[tid] + part[tid + 128];
  for (int id = tid; id < 50*32; id += 256) {
    int tl = id >> 5, f = id & 31;
    const float* w0 = p.cw + f*62;
    float acc = 0.f;
    #pragma unroll
    for (int k = 0; k < 31; ++k)
      acc += aw_s[tl+k]*w0[k] + awc_s[tl+k]*w0[31+k];
    loc_s[tl*33 + f] = acc;
  }
  __syncthreads();
  if (tid < 200) {
    int tl = tid >> 2, qa = tid & 3;
    int tt = t0 + tl;
    const __half* pm = p.pm16 + b*(TENC*ATTD) + tt*ATTD;
    float s = 0.f;
    for (int a = qa*32; a < qa*32 + 32; ++a) {
      const float* lw = p.ldw + a*32;
      float pl = 0.f;
      #pragma unroll 8
      for (int f = 0; f < 32; ++f) pl += loc_s[tl*33 + f] * lw[f];
      s += p.vw[a] * tanhf(pq_s[a] + __half2float(pm[a]) + pl);
    }
    epart[tl*4 + qa] = s;
  }
  __syncthreads();
  if (tid < 50) {
    int tt = t0 + tid;
    float v = epart[tid*4] + epart[tid*4+1] + epart[tid*4+2] + epart[tid*4+3];
    if (tt >= p.mlen[b]) v = -1000000000.0f;
    st_c(p.e + b*TENC + tt, v);
  }
  __syncthreads();
}

// =================== P3: softmax + LDS-resident ctx ===================
__device__ __forceinline__ void sm_ctx_phase(int bk, int t, const DecArgs& p,
  const float* awc_old, float* awc_new, float* ctx_cur, const __half2* mem_s,
  float* smem)
{
  int b = bk >> 3, jc = bk & 7, j0 = jc*96;
  int tid = threadIdx.x;
  float* red   = smem;         // 256
  float* aw_s  = smem + 256;   // 400
  float* cpart = smem + 656;   // 384
  float v0 = ld_c(p.e + b*TENC + tid);
  float v1 = (tid + 256 < TENC) ? ld_c(p.e + b*TENC + tid + 256) : -3.0e38f;
  red[tid] = fmaxf(v0, v1); __syncthreads();
  for (int s = 128; s > 0; s >>= 1) {
    if (tid < s) red[tid] = fmaxf(red[tid], red[tid+s]);
    __syncthreads();
  }
  float mx = red[0]; __syncthreads();
  float p0 = __expf(v0 - mx);
  float p1 = (tid + 256 < TENC) ? __expf(v1 - mx) : 0.f;
  red[tid] = p0 + p1; __syncthreads();
  for (int s = 128; s > 0; s >>= 1) {
    if (tid < s) red[tid] += red[tid+s];
    __syncthreads();
  }
  float inv = 1.f / red[0];
  aw_s[tid] = p0 * inv;
  if (tid + 256 < TENC) aw_s[tid + 256] = p1 * inv;
  __syncthreads();
  if (tid < 192) {
    int jp = tid % 48, h = tid / 48;
    float ax = 0.f, ay = 0.f;
    for (int tt = h*100; tt < h*100 + 100; ++tt) {
      float av = aw_s[tt];
      float2 m = __half22float2(mem_s[tt*48 + jp]);
      ax += av * m.x; ay += av * m.y;
    }
    cpart[(h*48 + jp)*2]     = ax;
    cpart[(h*48 + jp)*2 + 1] = ay;
  }
  __syncthreads();
  if (tid < 48) {
    float sx = cpart[tid*2]        + cpart[(48+tid)*2]
             + cpart[(96+tid)*2]   + cpart[(144+tid)*2];
    float sy = cpart[tid*2+1]      + cpart[(48+tid)*2+1]
             + cpart[(96+tid)*2+1] + cpart[(144+tid)*2+1];
    int j = j0 + tid*2;
    st_c(&p.ctxT[(size_t)j*32 + b], sx);
    st_c(&p.ctxT[(size_t)(j+1)*32 + b], sy);
    st_c(&ctx_cur[b*ENCD + j], sx);
    st_c(&ctx_cur[b*ENCD + j + 1], sy);
  }
  if (jc == 0) {
    for (int i = tid; i < TENC; i += 256) {
      float a = aw_s[i];
      st_c(&p.aw[b*TENC + i], a);
      st_c(&awc_new[b*TENC + i], ld_c(&awc_old[b*TENC + i]) + a);
      p.out_align[((size_t)b*TMEL + t)*TENC + i] = a;   // host-read after kernel end
    }
  }
  __syncthreads();
}

// =================== THE persistent kernel ===================
__global__ __launch_bounds__(256, 1) void decoder_loop(DecArgs p)
{
  __shared__ __align__(16) float scratch[12928];   // 51.7 KB (union)
  __shared__ __half2 mem_s[400*48];                // 76.8 KB (persistent)
  const int bk = blockIdx.x;
  const int u0 = bk * 4;
  unsigned phase = 0;

  { // preload memory slice (immutable -> cached loads)
    int b = bk >> 3, jc = bk & 7, j0 = jc*96;
    const float* mb = p.memory + (size_t)b*(TENC*ENCD);
    for (int idx = threadIdx.x; idx < 400*48; idx += 256) {
      int tt = idx / 48, jp = idx - tt*48;
      float m0 = mb[(size_t)tt*ENCD + j0 + jp*2];
      float m1 = mb[(size_t)tt*ENCD + j0 + jp*2 + 1];
      mem_s[idx] = __floats2half2_rn(m0, m1);
    }
  }
  __syncthreads();

  for (int t = 0; t < TMEL; ++t) {
    const float* ahT_rd  = p.ahT  + ((t+1)&1)*32768;
    float*       ahT_wr  = p.ahT  + (t&1)*32768;
    const float* dhT_rd  = p.dhT  + ((t+1)&1)*32768;
    float*       dhT_wr  = p.dhT  + (t&1)*32768;
    const float* awc_old = p.awcb + ((t+1)&1)*12800;
    float*       awc_new = p.awcb + (t&1)*12800;
    float*       ctx_cur = p.ctx2 + (t&1)*24576;
    const float* ctx_prev= p.ctx2 + ((t+1)&1)*24576;

    // P1: att-GEMM + cell (writes ahT, ah_row)
    gemm_cell(u0, false, p.xsT + (size_t)t*8192, 2, p.ctxT, 6, ahT_rd, 8,
              p.awih16, 1024, p.awhh16, p.abih, p.abhh,
              p.acT, ahT_wr, p.ah_row, scratch);
    gbar(p.bar, ++phase, bk);

    // P2: energies (+pq)
    energies_phase(bk, p, awc_old, scratch);
    gbar(p.bar, ++phase, bk);

    // P3: softmax + ctx (all blocks) + proj(t-1) (16 blocks)
    sm_ctx_phase(bk, t, p, awc_old, awc_new, ctx_cur, mem_s, scratch);
    if ((bk & 7) == 7 && (bk >> 3) < 16 && t > 0) {
      int d = (bk >> 3)*256 + threadIdx.x;
      proj_task(d, p.dh, ctx_prev, p.pw, p.pb, p.gw, p.gb,
                p.out_mel, p.out_gate, t-1);
    }
    gbar(p.bar, ++phase, bk);

    // P4: dec-GEMM + cell (writes dhT, dh)
    gemm_cell(u0, true, ahT_wr, 8, p.ctxT, 6, dhT_rd, 8,
              p.dwih16, 1792, p.dwhh16, p.dbih, p.dbhh,
              p.dcT, dhT_wr, p.dh, scratch);
    gbar(p.bar, ++phase, bk);
  }

  // final projection (t = TMEL-1)
  if ((bk & 7) == 7 && (bk >> 3) < 16) {
    int d = (bk >> 3)*256 + threadIdx.x;
    proj_task(d, p.dh, p.ctx2 + ((TMEL-1)&1)*24576, p.pw, p.pb, p.gw, p.gb,
              p.out_mel, p.out_gate, TMEL-1);
  }
}

extern "C" void kernel_launch(void* const* d_in, const int* in_sizes, int n_in,
                              void* d_out, int out_size, void* d_ws, size_t ws_size,
                              hipStream_t stream)
{
  const float* memory = (const float*)d_in[0];
  const float* din    = (const float*)d_in[1];
  const float* w1     = (const float*)d_in[3];
  const float* w2     = (const float*)d_in[4];
  const float* awih   = (const float*)d_in[5];
  const float* awhh   = (const float*)d_in[6];
  const float* abih   = (const float*)d_in[7];
  const float* abhh   = (const float*)d_in[8];
  const float* q_w    = (const float*)d_in[9];
  const float* mem_w  = (const float*)d_in[10];
  const float* v_w    = (const float*)d_in[11];
  const float* cw     = (const float*)d_in[12];
  const float* ldw    = (const float*)d_in[13];
  const float* dwih   = (const float*)d_in[14];
  const float* dwhh   = (const float*)d_in[15];
  const float* dbih   = (const float*)d_in[16];
  const float* dbhh   = (const float*)d_in[17];
  const float* pw     = (const float*)d_in[18];
  const float* pb     = (const float*)d_in[19];
  const float* gw     = (const float*)d_in[20];
  const float* gb     = (const float*)d_in[21];
  const int*   mlen   = (const int*)d_in[22];

  float* p = (float*)d_ws;
  float* xsT    = p;              p += 800*256*32;
  __half* awih16 = (__half*)p;    p += 2097152;
  __half* awhh16 = (__half*)p;    p += 2097152;
  __half* dwih16 = (__half*)p;    p += 3670016;
  __half* dwhh16 = (__half*)p;    p += 2097152;
  __half* qw16   = (__half*)p;    p += 65536;
  __half* pm16   = (__half*)p;    p += 819200;
  // ---- zeroed state block ----
  float* zs    = p;
  unsigned* bar = (unsigned*)p;   p += 320;
  float* ahT   = p;  p += 2*1024*32;
  float* dhT   = p;  p += 2*1024*32;
  float* dh    = p;  p += 32*1024;
  float* ah_row= p;  p += 32*1024;
  float* ctxT  = p;  p += 768*32;
  float* ctx2  = p;  p += 2*32*768;
  float* acT   = p;  p += 1024*32;
  float* dcT   = p;  p += 1024*32;
  float* aw    = p;  p += 32*400;
  float* awcb  = p;  p += 2*32*400;
  size_t zcount = (size_t)(p - zs);
  // ---- end zero block ----
  float* e     = p;  p += 32*400;

  float* out_mel   = (float*)d_out;
  float* out_gate  = out_mel + 32*80*800;
  float* out_align = out_gate + 32*800;

  hipMemsetAsync(zs, 0, zcount*sizeof(float), stream);
  prenet_kernel<<<TMEL, 256, 0, stream>>>(din, w1, w2, xsT);
  pmem_kernel<<<dim3(25,32), 256, 0, stream>>>(memory, mem_w, pm16);
  cvt16_kernel<<<256, 256, 0, stream>>>(q_w, qw16, 128*1024);
  cvt16_kernel<<<2048, 256, 0, stream>>>(awih, awih16, 4096*1024);
  cvt16_kernel<<<2048, 256, 0, stream>>>(awhh, awhh16, 4096*1024);
  cvt16_kernel<<<2048, 256, 0, stream>>>(dwih, dwih16, 4096*1792);
  cvt16_kernel<<<2048, 256, 0, stream>>>(dwhh, dwhh16, 4096*1024);

  DecArgs a;
  a.xsT = xsT;
  a.awih16 = awih16; a.awhh16 = awhh16; a.dwih16 = dwih16; a.dwhh16 = dwhh16;
  a.qw16 = qw16; a.pm16 = pm16;
  a.abih = abih; a.abhh = abhh; a.dbih = dbih; a.dbhh = dbhh;
  a.cw = cw; a.ldw = ldw; a.vw = v_w; a.mlen = mlen;
  a.pw = pw; a.pb = pb; a.gw = gw; a.gb = gb;
  a.ahT = ahT; a.acT = acT; a.dhT = dhT; a.dh = dh; a.dcT = dcT; a.ah_row = ah_row;
  a.ctxT = ctxT; a.ctx2 = ctx2; a.aw = aw; a.awcb = awcb; a.e = e;
  a.memory = memory;
  a.out_mel = out_mel; a.out_gate = out_gate; a.out_align = out_align;
  a.bar = bar;

  decoder_loop<<<NBLK, 256, 0, stream>>>(a);
}